// Round 2
// baseline (1711.272 us; speedup 1.0000x reference)
//
#include <hip/hip_runtime.h>

// Windowed attention block (B=32, C=128->256->128, H=W=112, WS=7, T=256 windows).
// All device I/O tensors are fp32 (per reference). Internal compute bf16 MFMA.
// Workspace layout (~617 MB):
//   QN [32][12544][128] bf16   (NHWC q, BN applied)
//   KN [32][12544][128] bf16
//   VW [32][256 j][12544 m] bf16, m = pq*256 + d
//   GN [32][12544][256] bf16   (gelu(attn out), NHWC)
//   params: sc512/sh512 (QKV BN fold), sco/sho (out BN fold, bias folded)

typedef unsigned short u16;
typedef unsigned int u32;

typedef short s16x8 __attribute__((ext_vector_type(8)));
typedef float f32x4 __attribute__((ext_vector_type(4)));
typedef u16 u16x8 __attribute__((ext_vector_type(8)));
typedef u16 u16x4 __attribute__((ext_vector_type(4)));

#define EPSV 1e-5f

__device__ __forceinline__ float bf2f(u16 h) {
  u32 u = ((u32)h) << 16;
  return __builtin_bit_cast(float, u);
}
__device__ __forceinline__ u16 f2bf(float f) {
  u32 u = __builtin_bit_cast(u32, f);
  u += 0x7FFFu + ((u >> 16) & 1u);
  return (u16)(u >> 16);
}
__device__ __forceinline__ s16x8 ld8(const u16* p) { return *(const s16x8*)p; }
// load 8 consecutive fp32, round to bf16 fragment
__device__ __forceinline__ s16x8 ldf8(const float* p) {
  const float4 f0 = *(const float4*)p;
  const float4 f1 = *(const float4*)(p + 4);
  s16x8 r;
  r[0] = (short)f2bf(f0.x); r[1] = (short)f2bf(f0.y);
  r[2] = (short)f2bf(f0.z); r[3] = (short)f2bf(f0.w);
  r[4] = (short)f2bf(f1.x); r[5] = (short)f2bf(f1.y);
  r[6] = (short)f2bf(f1.z); r[7] = (short)f2bf(f1.w);
  return r;
}
__device__ __forceinline__ f32x4 mfma_bf16(s16x8 a, s16x8 b, f32x4 c) {
  return __builtin_amdgcn_mfma_f32_16x16x32_bf16(a, b, c, 0, 0, 0);
}
__device__ __forceinline__ float gelu_f(float v) {
  // tanh-form gelu: v * sigmoid(1.59576912*(v + 0.044715 v^3)); max err ~3e-4
  float e = exp2f(-2.3022083f * (v + 0.044715f * v * v * v));
  return v / (1.0f + e);
}

// ---------------- K0: fold BN params ----------------
__global__ void k_params(
    const float* __restrict__ gq, const float* __restrict__ bq, const float* __restrict__ mq, const float* __restrict__ vq,
    const float* __restrict__ gk, const float* __restrict__ bk, const float* __restrict__ mk, const float* __restrict__ vk,
    const float* __restrict__ gv, const float* __restrict__ bv, const float* __restrict__ mv, const float* __restrict__ vv,
    const float* __restrict__ bo, const float* __restrict__ go, const float* __restrict__ bbo, const float* __restrict__ mo,
    const float* __restrict__ vo,
    float* __restrict__ sc512, float* __restrict__ sh512, float* __restrict__ sco, float* __restrict__ sho)
{
  const int i = threadIdx.x;
  if (i < 128) {
    const float s = gq[i] * rsqrtf(vq[i] + EPSV);
    sc512[i] = s;
    sh512[i] = bq[i] - mq[i] * s;
    const float so = go[i] * rsqrtf(vo[i] + EPSV);
    sco[i] = so;
    sho[i] = (bo[i] - mo[i]) * so + bbo[i];
  } else if (i < 256) {
    const int c = i - 128;
    const float s = gk[c] * rsqrtf(vk[c] + EPSV);
    sc512[i] = s;
    sh512[i] = bk[c] - mk[c] * s;
  } else if (i < 512) {
    const int c = i - 256;
    const float s = gv[c] * rsqrtf(vv[c] + EPSV);
    sc512[i] = s;
    sh512[i] = bv[c] - mv[c] * s;
  }
}

// ---------------- K1: QKV projection + BN ----------------
// block: (px-tile of 256, b). 256 threads = 4 waves. Each wave: 64 px x all 512 co.
__global__ __launch_bounds__(256, 2) void k_qkv(
    const float* __restrict__ x, const float* __restrict__ wq,
    const float* __restrict__ wk, const float* __restrict__ wv,
    const float* __restrict__ sc512, const float* __restrict__ sh512,
    u16* __restrict__ QN, u16* __restrict__ KN, u16* __restrict__ VW)
{
  __shared__ u16 XT[256 * 128];  // [px][c ^ ((px&15)<<3)] bf16
  const int b = blockIdx.y;
  const int px0 = blockIdx.x * 256;
  const int t = threadIdx.x;

  // stage x tile (NCHW fp32 -> LDS bf16 transposed, XOR-swizzled)
  {
    const float* xp = x + (size_t)b * 128u * 12544u + (size_t)(px0 + t);
    const int sw = (t & 15) << 3;
    #pragma unroll 8
    for (int c = 0; c < 128; c += 4) {
      u16x4 pk;
      pk[0] = f2bf(xp[(size_t)(c + 0) * 12544u]);
      pk[1] = f2bf(xp[(size_t)(c + 1) * 12544u]);
      pk[2] = f2bf(xp[(size_t)(c + 2) * 12544u]);
      pk[3] = f2bf(xp[(size_t)(c + 3) * 12544u]);
      *(u16x4*)&XT[t * 128 + (c ^ sw)] = pk;
    }
  }
  __syncthreads();

  const int w = t >> 6, l = t & 63, a15 = l & 15, g = l >> 4;

  // A fragments: [64 px][128 c] for this wave
  s16x8 af[4][4];
  #pragma unroll
  for (int pxt = 0; pxt < 4; ++pxt) {
    const int row = w * 64 + pxt * 16 + a15;
    const int sw = (row & 15) << 3;
    #pragma unroll
    for (int ks = 0; ks < 4; ++ks) {
      const int cc = ks * 32 + g * 8;
      af[pxt][ks] = *(const s16x8*)&XT[row * 128 + (cc ^ sw)];
    }
  }

  // output row bases (per-lane, fixed across cot)
  u32 qidx[4][4];
  u32 vidx[4][4];
  #pragma unroll
  for (int pxt = 0; pxt < 4; ++pxt) {
    #pragma unroll
    for (int r = 0; r < 4; ++r) {
      const int px = px0 + w * 64 + pxt * 16 + g * 4 + r;
      qidx[pxt][r] = ((u32)b * 12544u + (u32)px) * 128u;
      const int hh = px / 112, ww = px - hh * 112;
      const int h1 = hh / 7, p = hh - h1 * 7;
      const int w1 = ww / 7, q = ww - w1 * 7;
      const int j = h1 * 16 + w1, pq = p * 7 + q;
      vidx[pxt][r] = ((u32)b * 256u + (u32)j) * 12544u + (u32)(pq * 256);
    }
  }

  #pragma unroll 1
  for (int cot = 0; cot < 32; ++cot) {
    const int co = cot * 16 + a15;
    const float* wrow;
    if (cot < 8)       wrow = wq + (u32)co * 128u;
    else if (cot < 16) wrow = wk + (u32)(co - 128) * 128u;
    else               wrow = wv + (u32)(co - 256) * 128u;
    s16x8 bfr[4];
    #pragma unroll
    for (int ks = 0; ks < 4; ++ks) bfr[ks] = ldf8(wrow + ks * 32 + g * 8);

    f32x4 acc[4];
    #pragma unroll
    for (int pxt = 0; pxt < 4; ++pxt) { acc[pxt][0]=0.f; acc[pxt][1]=0.f; acc[pxt][2]=0.f; acc[pxt][3]=0.f; }
    #pragma unroll
    for (int ks = 0; ks < 4; ++ks)
      #pragma unroll
      for (int pxt = 0; pxt < 4; ++pxt)
        acc[pxt] = mfma_bf16(af[pxt][ks], bfr[ks], acc[pxt]);

    const float sc = sc512[co], sh = sh512[co];
    if (cot < 8) {
      #pragma unroll
      for (int pxt = 0; pxt < 4; ++pxt)
        #pragma unroll
        for (int r = 0; r < 4; ++r)
          QN[qidx[pxt][r] + (u32)co] = f2bf(acc[pxt][r] * sc + sh);
    } else if (cot < 16) {
      #pragma unroll
      for (int pxt = 0; pxt < 4; ++pxt)
        #pragma unroll
        for (int r = 0; r < 4; ++r)
          KN[qidx[pxt][r] + (u32)(co - 128)] = f2bf(acc[pxt][r] * sc + sh);
    } else {
      #pragma unroll
      for (int pxt = 0; pxt < 4; ++pxt)
        #pragma unroll
        for (int r = 0; r < 4; ++r)
          VW[vidx[pxt][r] + (u32)(co - 256)] = f2bf(acc[pxt][r] * sc + sh);
    }
  }
}

// ---------------- K2: dots + softmax + PV + gelu ----------------
// block: (i-tile of 32, b). 512 threads = 8 waves.
__global__ __launch_bounds__(512, 2) void k_attn(
    const u16* __restrict__ QN, const u16* __restrict__ KN,
    const u16* __restrict__ VW, u16* __restrict__ GN)
{
  __shared__ u16 P[32 * 264];                 // P bf16, padded rows
  __shared__ __align__(16) float statsM[32 * 4];
  __shared__ __align__(16) float statsS[32 * 4];
  __shared__ u16 KV[256 * 72];                // K chunk [256 j][64+8]; reused as Vt [64 m][264]

  const int b = blockIdx.y;
  const int i0 = blockIdx.x * 32;
  const int t = threadIdx.x;
  const int w8 = t >> 6, l = t & 63, a15 = l & 15, g = l >> 4;
  const int jq = (w8 & 3) * 64;   // j quarter for dots
  const int ih = w8 >> 2;         // i half

  // ----- phase A: dots -----
  f32x4 accA[4];
  #pragma unroll
  for (int jt = 0; jt < 4; ++jt) { accA[jt][0]=0.f; accA[jt][1]=0.f; accA[jt][2]=0.f; accA[jt][3]=0.f; }

  int ibase;
  { const int i = i0 + ih * 16 + a15; ibase = (i >> 4) * 784 + (i & 15) * 7; }
  const int jj = t & 255;
  const int jpx_base = (jj >> 4) * 784 + (jj & 15) * 7;
  const int khalf = (t >> 8) * 32;

  for (int ch = 0; ch < 98; ++ch) {
    const int pq = ch >> 1;
    const int c1_0 = (ch & 1) * 64;
    const int pp = pq / 7, qq = pq - 7 * pp;
    const int ppq = pp * 112 + qq;
    // stage K chunk [256 j][64 kk]
    {
      const u16* src = KN + ((u32)b * 12544u + (u32)(jpx_base + ppq)) * 128u + (u32)(c1_0 + khalf);
      u16* dst = &KV[jj * 72 + khalf];
      #pragma unroll
      for (int ii = 0; ii < 4; ++ii)
        *(u16x8*)(dst + ii * 8) = *(const u16x8*)(src + ii * 8);
    }
    __syncthreads();
    s16x8 a0, a1;
    {
      const u32 ab = ((u32)b * 12544u + (u32)(ibase + ppq)) * 128u + (u32)(c1_0 + g * 8);
      a0 = ld8(QN + ab);
      a1 = ld8(QN + ab + 32);
    }
    #pragma unroll
    for (int jt = 0; jt < 4; ++jt) {
      const int jrow = jq + jt * 16 + a15;
      const s16x8 b0 = *(const s16x8*)&KV[jrow * 72 + g * 8];
      const s16x8 b1 = *(const s16x8*)&KV[jrow * 72 + 32 + g * 8];
      accA[jt] = mfma_bf16(a0, b0, accA[jt]);
      accA[jt] = mfma_bf16(a1, b1, accA[jt]);
    }
    __syncthreads();
  }

  // ----- softmax (scale folded into exponent) -----
  const float CEXP = 0.18033688f;  // 0.125 * log2(e)
  float rmax[4], rinv[4];
  #pragma unroll
  for (int r = 0; r < 4; ++r) {
    float m = fmaxf(fmaxf(accA[0][r], accA[1][r]), fmaxf(accA[2][r], accA[3][r]));
    m = fmaxf(m, __shfl_xor(m, 1));
    m = fmaxf(m, __shfl_xor(m, 2));
    m = fmaxf(m, __shfl_xor(m, 4));
    m = fmaxf(m, __shfl_xor(m, 8));
    if (a15 == 0) statsM[(ih * 16 + g * 4 + r) * 4 + (w8 & 3)] = m;
  }
  __syncthreads();
  #pragma unroll
  for (int r = 0; r < 4; ++r) {
    const float4 s4 = *(const float4*)&statsM[(ih * 16 + g * 4 + r) * 4];
    rmax[r] = fmaxf(fmaxf(s4.x, s4.y), fmaxf(s4.z, s4.w));
  }
  #pragma unroll
  for (int r = 0; r < 4; ++r) {
    float s = 0.f;
    #pragma unroll
    for (int jt = 0; jt < 4; ++jt) {
      const float p = exp2f((accA[jt][r] - rmax[r]) * CEXP);
      accA[jt][r] = p;
      s += p;
    }
    s += __shfl_xor(s, 1);
    s += __shfl_xor(s, 2);
    s += __shfl_xor(s, 4);
    s += __shfl_xor(s, 8);
    if (a15 == 0) statsS[(ih * 16 + g * 4 + r) * 4 + (w8 & 3)] = s;
  }
  __syncthreads();
  #pragma unroll
  for (int r = 0; r < 4; ++r) {
    const float4 s4 = *(const float4*)&statsS[(ih * 16 + g * 4 + r) * 4];
    rinv[r] = 1.0f / (s4.x + s4.y + s4.z + s4.w);
  }
  #pragma unroll
  for (int r = 0; r < 4; ++r) {
    const int irow = ih * 16 + g * 4 + r;
    #pragma unroll
    for (int jt = 0; jt < 4; ++jt)
      P[irow * 264 + jq + jt * 16 + a15] = f2bf(accA[jt][r] * rinv[r]);
  }
  __syncthreads();

  // ----- phase B: PV + gelu -----
  u16* Vt = KV;  // [64 m][264]
  const int sj0 = (t & 31) * 8;
  const int sms = (t >> 5) * 4;
  const u16* vbase = VW + ((u32)b * 256u + (u32)sj0) * 12544u + (u32)sms;
  u32 gbase[4];
  #pragma unroll
  for (int r = 0; r < 4; ++r) {
    const int i = i0 + ih * 16 + g * 4 + r;
    const int ib = (i >> 4) * 784 + (i & 15) * 7;
    gbase[r] = ((u32)b * 12544u + (u32)ib) * 256u + (u32)a15;
  }
  const int mstrip = (w8 & 3) * 16;

  #pragma unroll 1
  for (int mc = 0; mc < 196; ++mc) {
    const u32 m0 = (u32)mc * 64u;
    // stage V chunk transposed: VW[b][j][m] -> Vt[m][j]
    {
      u16x4 rr[8];
      #pragma unroll
      for (int ji = 0; ji < 8; ++ji)
        rr[ji] = *(const u16x4*)(vbase + (u32)ji * 12544u + m0);
      #pragma unroll
      for (int mi = 0; mi < 4; ++mi) {
        u16x8 wv;
        wv[0] = rr[0][mi]; wv[1] = rr[1][mi]; wv[2] = rr[2][mi]; wv[3] = rr[3][mi];
        wv[4] = rr[4][mi]; wv[5] = rr[5][mi]; wv[6] = rr[6][mi]; wv[7] = rr[7][mi];
        *(u16x8*)&Vt[(sms + mi) * 264 + sj0] = wv;
      }
    }
    __syncthreads();
    const int mloc = mstrip + a15;
    f32x4 acc; acc[0]=0.f; acc[1]=0.f; acc[2]=0.f; acc[3]=0.f;
    #pragma unroll
    for (int ks = 0; ks < 8; ++ks) {
      const s16x8 bfr = *(const s16x8*)&Vt[mloc * 264 + ks * 32 + g * 8];
      const s16x8 ar  = *(const s16x8*)&P[(ih * 16 + a15) * 264 + ks * 32 + g * 8];
      acc = mfma_bf16(ar, bfr, acc);
    }
    const u32 m_base = m0 + (u32)mstrip;
    const int pqv = (int)(m_base >> 8);
    const u32 dbase = m_base & 255u;
    const int pp = pqv / 7, qq = pqv - 7 * pp;
    const u32 poff = (u32)(pp * 112 + qq) * 256u + dbase;
    #pragma unroll
    for (int r = 0; r < 4; ++r)
      GN[gbase[r] + poff] = f2bf(gelu_f(acc[r]));
    __syncthreads();
  }
}

// ---------------- K3: out conv + BN + residual + gelu ----------------
__global__ __launch_bounds__(256, 2) void k_out(
    const u16* __restrict__ GN, const float* __restrict__ wo,
    const float* __restrict__ x, const float* __restrict__ sco,
    const float* __restrict__ sho, float* __restrict__ out)
{
  __shared__ u16 OT[128 * 264];  // [o][px] bf16 (BN applied, pre-residual)
  const int b = blockIdx.y;
  const int px0 = blockIdx.x * 256;
  const int t = threadIdx.x;
  const int w = t >> 6, l = t & 63, a15 = l & 15, g = l >> 4;

  #pragma unroll 1
  for (int pxt = 0; pxt < 4; ++pxt) {
    const int pxl = w * 64 + pxt * 16;
    s16x8 af[8];
    const u32 ab = ((u32)b * 12544u + (u32)(px0 + pxl + a15)) * 256u + (u32)(g * 8);
    #pragma unroll
    for (int ks = 0; ks < 8; ++ks) af[ks] = ld8(GN + ab + ks * 32);
    #pragma unroll 1
    for (int ot = 0; ot < 8; ++ot) {
      const int o = ot * 16 + a15;
      f32x4 acc; acc[0]=0.f; acc[1]=0.f; acc[2]=0.f; acc[3]=0.f;
      #pragma unroll
      for (int ks = 0; ks < 8; ++ks) {
        const s16x8 bfw = ldf8(wo + (u32)o * 256u + (u32)(ks * 32 + g * 8));
        acc = mfma_bf16(af[ks], bfw, acc);
      }
      const float s = sco[o], sh = sho[o];
      u16x4 pk;
      pk[0] = f2bf(acc[0] * s + sh);
      pk[1] = f2bf(acc[1] * s + sh);
      pk[2] = f2bf(acc[2] * s + sh);
      pk[3] = f2bf(acc[3] * s + sh);
      *(u16x4*)&OT[o * 264 + pxl + g * 4] = pk;
    }
  }
  __syncthreads();
  // residual + gelu, coalesced NCHW store (fp32)
  const int o2 = t >> 1;
  const int ph = (t & 1) * 128;
  const size_t xb = ((size_t)b * 128u + (size_t)o2) * 12544u + (size_t)(px0 + ph);
  #pragma unroll 4
  for (int ii = 0; ii < 16; ++ii) {
    const u16x8 zt = *(const u16x8*)&OT[o2 * 264 + ph + ii * 8];
    const float4 xv0 = *(const float4*)(x + xb + ii * 8);
    const float4 xv1 = *(const float4*)(x + xb + ii * 8 + 4);
    float4 r0, r1;
    r0.x = gelu_f(bf2f(zt[0]) + xv0.x);
    r0.y = gelu_f(bf2f(zt[1]) + xv0.y);
    r0.z = gelu_f(bf2f(zt[2]) + xv0.z);
    r0.w = gelu_f(bf2f(zt[3]) + xv0.w);
    r1.x = gelu_f(bf2f(zt[4]) + xv1.x);
    r1.y = gelu_f(bf2f(zt[5]) + xv1.y);
    r1.z = gelu_f(bf2f(zt[6]) + xv1.z);
    r1.w = gelu_f(bf2f(zt[7]) + xv1.w);
    *(float4*)(out + xb + ii * 8) = r0;
    *(float4*)(out + xb + ii * 8 + 4) = r1;
  }
}

extern "C" void kernel_launch(void* const* d_in, const int* in_sizes, int n_in,
                              void* d_out, int out_size, void* d_ws, size_t ws_size,
                              hipStream_t stream) {
  (void)in_sizes; (void)n_in; (void)out_size; (void)ws_size;
  const float* x   = (const float*)d_in[0];
  const float* wq  = (const float*)d_in[1];
  const float* gq  = (const float*)d_in[2];
  const float* bq  = (const float*)d_in[3];
  const float* mq  = (const float*)d_in[4];
  const float* vq  = (const float*)d_in[5];
  const float* wk  = (const float*)d_in[6];
  const float* gk  = (const float*)d_in[7];
  const float* bk  = (const float*)d_in[8];
  const float* mk  = (const float*)d_in[9];
  const float* vk  = (const float*)d_in[10];
  const float* wv  = (const float*)d_in[11];
  const float* gv  = (const float*)d_in[12];
  const float* bv  = (const float*)d_in[13];
  const float* mv  = (const float*)d_in[14];
  const float* vv  = (const float*)d_in[15];
  const float* wo  = (const float*)d_in[16];
  const float* bo  = (const float*)d_in[17];
  const float* go  = (const float*)d_in[18];
  const float* bbo = (const float*)d_in[19];
  const float* mo  = (const float*)d_in[20];
  const float* vo  = (const float*)d_in[21];

  u16* QN = (u16*)d_ws;
  u16* KN = QN + 51380224u;     // 32*12544*128
  u16* VW = KN + 51380224u;
  u16* GN = VW + 102760448u;    // 32*256*12544
  float* sc512 = (float*)(GN + 102760448u);
  float* sh512 = sc512 + 512;
  float* sco = sh512 + 512;
  float* sho = sco + 128;

  k_params<<<1, 512, 0, stream>>>(gq, bq, mq, vq, gk, bk, mk, vk, gv, bv, mv, vv,
                                  bo, go, bbo, mo, vo, sc512, sh512, sco, sho);
  k_qkv<<<dim3(49, 32), 256, 0, stream>>>(x, wq, wk, wv, sc512, sh512, QN, KN, VW);
  k_attn<<<dim3(8, 32), 512, 0, stream>>>(QN, KN, VW, GN);
  k_out<<<dim3(49, 32), 256, 0, stream>>>(GN, wo, x, sco, sho, (float*)d_out);
}

// Round 3
// 748.808 us; speedup vs baseline: 2.2853x; 2.2853x over previous
//
#include <hip/hip_runtime.h>

// Windowed attention block (B=32, C=128->256->128, H=W=112, WS=7, T=256 windows).
// fp32 I/O, bf16 MFMA internal.
// ws (616.6MB): QW [32][256 j][49 pq *128c] bf16 | KW same | VW [32][256 j][12544 m] bf16
//               GN [32][12544 px][256 d] bf16 | params f32
// aliases: P bf16 [32][256][256] -> QW base (after k_dots reads QW)
//          Pp f32 [8][32][256][256] -> GN base (before k_pv writes GN)
//          wfused bf16 [512][128] -> GN base (dead before k_dots writes Pp)

typedef unsigned short u16;
typedef unsigned int u32;
typedef short s16x8 __attribute__((ext_vector_type(8)));
typedef float f32x4 __attribute__((ext_vector_type(4)));
typedef u16 u16x8 __attribute__((ext_vector_type(8)));
typedef u16 u16x4 __attribute__((ext_vector_type(4)));

#define EPSV 1e-5f

__device__ __forceinline__ float bf2f(u16 h) {
  u32 u = ((u32)h) << 16;
  return __builtin_bit_cast(float, u);
}
__device__ __forceinline__ u16 f2bf(float f) {
  u32 u = __builtin_bit_cast(u32, f);
  u += 0x7FFFu + ((u >> 16) & 1u);
  return (u16)(u >> 16);
}
__device__ __forceinline__ s16x8 ld8(const u16* p) { return *(const s16x8*)p; }
__device__ __forceinline__ f32x4 mfma_bf16(s16x8 a, s16x8 b, f32x4 c) {
  return __builtin_amdgcn_mfma_f32_16x16x32_bf16(a, b, c, 0, 0, 0);
}
__device__ __forceinline__ float gelu_f(float v) {
  float e = exp2f(-2.3022083f * (v + 0.044715f * v * v * v));
  return v / (1.0f + e);
}

// ---------------- K0: fold BN params ----------------
__global__ void k_params(
    const float* __restrict__ gq, const float* __restrict__ bq, const float* __restrict__ mq, const float* __restrict__ vq,
    const float* __restrict__ gk, const float* __restrict__ bk, const float* __restrict__ mk, const float* __restrict__ vk,
    const float* __restrict__ gv, const float* __restrict__ bv, const float* __restrict__ mv, const float* __restrict__ vv,
    const float* __restrict__ bo, const float* __restrict__ go, const float* __restrict__ bbo, const float* __restrict__ mo,
    const float* __restrict__ vo,
    float* __restrict__ sc512, float* __restrict__ sh512, float* __restrict__ sco, float* __restrict__ sho)
{
  const int i = threadIdx.x;
  if (i < 128) {
    const float s = gq[i] * rsqrtf(vq[i] + EPSV);
    sc512[i] = s;
    sh512[i] = bq[i] - mq[i] * s;
    const float so = go[i] * rsqrtf(vo[i] + EPSV);
    sco[i] = so;
    sho[i] = (bo[i] - mo[i]) * so + bbo[i];
  } else if (i < 256) {
    const int c = i - 128;
    const float s = gk[c] * rsqrtf(vk[c] + EPSV);
    sc512[i] = s;
    sh512[i] = bk[c] - mk[c] * s;
  } else if (i < 512) {
    const int c = i - 256;
    const float s = gv[c] * rsqrtf(vv[c] + EPSV);
    sc512[i] = s;
    sh512[i] = bv[c] - mv[c] * s;
  }
}

// ---------------- K0b: convert+scale-fold QKV weights to bf16 ----------------
__global__ void k_wconv(const float* __restrict__ wq, const float* __restrict__ wk,
                        const float* __restrict__ wv, const float* __restrict__ sc512,
                        u16* __restrict__ wfused)
{
  const int idx4 = (blockIdx.x * 256 + threadIdx.x) * 4;  // 0..65532
  const int co = idx4 >> 7, c = idx4 & 127;
  const float* src = (co < 128) ? (wq + co * 128 + c)
                   : (co < 256) ? (wk + (co - 128) * 128 + c)
                                : (wv + (co - 256) * 128 + c);
  const float s = sc512[co];
  const float4 v = *(const float4*)src;
  u16x4 r;
  r[0] = f2bf(v.x * s); r[1] = f2bf(v.y * s);
  r[2] = f2bf(v.z * s); r[3] = f2bf(v.w * s);
  *(u16x4*)(wfused + idx4) = r;
}

// ---------------- K1: QKV projection (+folded BN) ----------------
__global__ __launch_bounds__(256, 2) void k_qkv(
    const float* __restrict__ x, const u16* __restrict__ wfused,
    const float* __restrict__ sh512,
    u16* __restrict__ QW, u16* __restrict__ KW, u16* __restrict__ VW)
{
  __shared__ u16 XT[256 * 128];  // [px][c ^ ((px&15)<<3)] bf16
  const int b = blockIdx.y;
  const int px0 = blockIdx.x * 256;
  const int t = threadIdx.x;

  {
    const float* xp = x + (size_t)b * 128u * 12544u + (size_t)(px0 + t);
    const int sw = (t & 15) << 3;
    #pragma unroll 8
    for (int c = 0; c < 128; c += 4) {
      u16x4 pk;
      pk[0] = f2bf(xp[(size_t)(c + 0) * 12544u]);
      pk[1] = f2bf(xp[(size_t)(c + 1) * 12544u]);
      pk[2] = f2bf(xp[(size_t)(c + 2) * 12544u]);
      pk[3] = f2bf(xp[(size_t)(c + 3) * 12544u]);
      *(u16x4*)&XT[t * 128 + (c ^ sw)] = pk;
    }
  }
  __syncthreads();

  const int w = t >> 6, l = t & 63, a15 = l & 15, g = l >> 4;

  s16x8 af[4][4];
  #pragma unroll
  for (int pxt = 0; pxt < 4; ++pxt) {
    const int row = w * 64 + pxt * 16 + a15;
    const int sw = (row & 15) << 3;
    #pragma unroll
    for (int ks = 0; ks < 4; ++ks) {
      const int cc = ks * 32 + g * 8;
      af[pxt][ks] = *(const s16x8*)&XT[row * 128 + (cc ^ sw)];
    }
  }

  u32 qkidx[4][4], vidx[4][4];
  #pragma unroll
  for (int pxt = 0; pxt < 4; ++pxt) {
    #pragma unroll
    for (int r = 0; r < 4; ++r) {
      const int px = px0 + w * 64 + pxt * 16 + g * 4 + r;
      const int hh = px / 112, ww = px - hh * 112;
      const int h1 = hh / 7, p = hh - h1 * 7;
      const int w1 = ww / 7, q = ww - w1 * 7;
      const int j = h1 * 16 + w1, pq = p * 7 + q;
      qkidx[pxt][r] = ((u32)(b * 256 + j) * 49u + (u32)pq) * 128u;
      vidx[pxt][r] = (u32)(b * 256 + j) * 12544u + (u32)(pq * 256);
    }
  }

  #pragma unroll 1
  for (int cot = 0; cot < 32; ++cot) {
    const int co = cot * 16 + a15;
    const u16* wrow = wfused + (u32)co * 128u;
    s16x8 bfr[4];
    #pragma unroll
    for (int ks = 0; ks < 4; ++ks) bfr[ks] = ld8(wrow + ks * 32 + g * 8);

    f32x4 acc[4];
    #pragma unroll
    for (int pxt = 0; pxt < 4; ++pxt) { acc[pxt][0]=0.f; acc[pxt][1]=0.f; acc[pxt][2]=0.f; acc[pxt][3]=0.f; }
    #pragma unroll
    for (int ks = 0; ks < 4; ++ks)
      #pragma unroll
      for (int pxt = 0; pxt < 4; ++pxt)
        acc[pxt] = mfma_bf16(af[pxt][ks], bfr[ks], acc[pxt]);

    const float sh = sh512[co];
    if (cot < 8) {
      #pragma unroll
      for (int pxt = 0; pxt < 4; ++pxt)
        #pragma unroll
        for (int r = 0; r < 4; ++r)
          QW[qkidx[pxt][r] + (u32)co] = f2bf(acc[pxt][r] + sh);
    } else if (cot < 16) {
      #pragma unroll
      for (int pxt = 0; pxt < 4; ++pxt)
        #pragma unroll
        for (int r = 0; r < 4; ++r)
          KW[qkidx[pxt][r] + (u32)(co - 128)] = f2bf(acc[pxt][r] + sh);
    } else {
      #pragma unroll
      for (int pxt = 0; pxt < 4; ++pxt)
        #pragma unroll
        for (int r = 0; r < 4; ++r)
          VW[vidx[pxt][r] + (u32)(co - 256)] = f2bf(acc[pxt][r] + sh);
    }
  }
}

// ---------------- K2: dots partials (split-K over pq) ----------------
// grid (8 ks, 32 b), 512 thr. Block: full 256i x 256j over k = 768 (or 896).
__global__ __launch_bounds__(512, 2) void k_dots(
    const u16* __restrict__ QW, const u16* __restrict__ KW, float* __restrict__ Pp)
{
  __shared__ u16 QS[256 * 64];  // [i][k ^ ((i&7)<<3)]
  __shared__ u16 KS[256 * 64];
  const int b = blockIdx.y, ks = blockIdx.x;
  const int nch = (ks == 7) ? 14 : 12;
  const int t = threadIdx.x;
  const int w = t >> 6, l = t & 63, a15 = l & 15, g = l >> 4;
  const int i0w = (w >> 1) * 64, j0w = (w & 1) * 128;

  f32x4 acc[4][8];
  #pragma unroll
  for (int i = 0; i < 4; ++i)
    #pragma unroll
    for (int j = 0; j < 8; ++j) { acc[i][j][0]=0.f; acc[i][j][1]=0.f; acc[i][j][2]=0.f; acc[i][j][3]=0.f; }

  const int srow = t >> 1;
  const int sgr0 = (t & 1) * 4;
  const size_t kb = (size_t)ks * 768 + (size_t)((t & 1) * 32);
  const u16* qsrc = QW + ((size_t)b * 256 + srow) * 6272 + kb;
  const u16* ksrc = KW + ((size_t)b * 256 + srow) * 6272 + kb;
  u16* qdst = &QS[srow * 64];
  u16* kdst = &KS[srow * 64];
  const int swr = srow & 7;

  for (int ch = 0; ch < nch; ++ch) {
    const int k0 = ch * 64;
    #pragma unroll
    for (int gi = 0; gi < 4; ++gi) {
      const int off = ((sgr0 + gi) ^ swr) << 3;
      *(u16x8*)(qdst + off) = *(const u16x8*)(qsrc + k0 + gi * 8);
      *(u16x8*)(kdst + off) = *(const u16x8*)(ksrc + k0 + gi * 8);
    }
    __syncthreads();
    #pragma unroll
    for (int kk = 0; kk < 2; ++kk) {
      s16x8 af[4], bfr[8];
      #pragma unroll
      for (int i4 = 0; i4 < 4; ++i4) {
        const int ir = i0w + i4 * 16 + a15;
        af[i4] = *(const s16x8*)&QS[ir * 64 + (((kk * 4 + g) ^ (ir & 7)) << 3)];
      }
      #pragma unroll
      for (int j8 = 0; j8 < 8; ++j8) {
        const int jr = j0w + j8 * 16 + a15;
        bfr[j8] = *(const s16x8*)&KS[jr * 64 + (((kk * 4 + g) ^ (jr & 7)) << 3)];
      }
      #pragma unroll
      for (int i4 = 0; i4 < 4; ++i4)
        #pragma unroll
        for (int j8 = 0; j8 < 8; ++j8)
          acc[i4][j8] = mfma_bf16(af[i4], bfr[j8], acc[i4][j8]);
    }
    __syncthreads();
  }

  float* pp = Pp + ((size_t)ks * 32 + b) * 256 * 256;
  #pragma unroll
  for (int i4 = 0; i4 < 4; ++i4)
    #pragma unroll
    for (int r = 0; r < 4; ++r) {
      const int ir = i0w + i4 * 16 + g * 4 + r;
      #pragma unroll
      for (int j8 = 0; j8 < 8; ++j8)
        pp[(size_t)ir * 256 + j0w + j8 * 16 + a15] = acc[i4][j8][r];
    }
}

// ---------------- K3: reduce partials + softmax -> P bf16 ----------------
__global__ __launch_bounds__(256, 4) void k_smax(const float* __restrict__ Pp, u16* __restrict__ P)
{
  const int b = blockIdx.y, it = blockIdx.x;
  const int t = threadIdx.x;
  const int row = it * 32 + (t >> 3);
  const int cg = t & 7;
  const size_t rb = ((size_t)b * 256 + row) * 256 + cg * 32;

  f32x4 s[8];
  #pragma unroll
  for (int cc = 0; cc < 8; ++cc) { s[cc][0]=0.f; s[cc][1]=0.f; s[cc][2]=0.f; s[cc][3]=0.f; }
  #pragma unroll 1
  for (int ks = 0; ks < 8; ++ks) {
    const float* src = Pp + (size_t)ks * 32 * 256 * 256 + rb;
    #pragma unroll
    for (int cc = 0; cc < 8; ++cc)
      s[cc] += *(const f32x4*)(src + cc * 4);
  }
  float m = -1e30f;
  #pragma unroll
  for (int cc = 0; cc < 8; ++cc)
    m = fmaxf(m, fmaxf(fmaxf(s[cc][0], s[cc][1]), fmaxf(s[cc][2], s[cc][3])));
  m = fmaxf(m, __shfl_xor(m, 1));
  m = fmaxf(m, __shfl_xor(m, 2));
  m = fmaxf(m, __shfl_xor(m, 4));
  const float CEXP = 0.18033688f;  // 0.125*log2(e)
  float sum = 0.f;
  #pragma unroll
  for (int cc = 0; cc < 8; ++cc)
    #pragma unroll
    for (int e = 0; e < 4; ++e) {
      const float p = exp2f((s[cc][e] - m) * CEXP);
      s[cc][e] = p;
      sum += p;
    }
  sum += __shfl_xor(sum, 1);
  sum += __shfl_xor(sum, 2);
  sum += __shfl_xor(sum, 4);
  const float inv = 1.0f / sum;
  u16* dst = P + rb;
  #pragma unroll
  for (int cc = 0; cc < 8; cc += 2) {
    u16x8 o;
    o[0] = f2bf(s[cc][0] * inv);     o[1] = f2bf(s[cc][1] * inv);
    o[2] = f2bf(s[cc][2] * inv);     o[3] = f2bf(s[cc][3] * inv);
    o[4] = f2bf(s[cc + 1][0] * inv); o[5] = f2bf(s[cc + 1][1] * inv);
    o[6] = f2bf(s[cc + 1][2] * inv); o[7] = f2bf(s[cc + 1][3] * inv);
    *(u16x8*)(dst + cc * 4) = o;
  }
}

// ---------------- K4: PV + gelu -> GN ----------------
// grid (49 pq, 32 b), 512 thr. Block: 256 m (=d within pq) x 256 i, K=256 j in 4 chunks.
__global__ __launch_bounds__(512, 2) void k_pv(
    const u16* __restrict__ P, const u16* __restrict__ VW, u16* __restrict__ GN)
{
  __shared__ u16 VT[256 * 64];  // [m][j ^ ((m&7)<<3)]
  __shared__ u16 PS[256 * 64];  // [i][j ^ ((i&7)<<3)]
  const int b = blockIdx.y, pq = blockIdx.x;
  const int t = threadIdx.x;
  const int w = t >> 6, l = t & 63, a15 = l & 15, g = l >> 4;
  const int m0w = (w >> 1) * 64, i0w = (w & 1) * 128;

  f32x4 acc[4][8];  // [mf][if]
  #pragma unroll
  for (int i = 0; i < 4; ++i)
    #pragma unroll
    for (int j = 0; j < 8; ++j) { acc[i][j][0]=0.f; acc[i][j][1]=0.f; acc[i][j][2]=0.f; acc[i][j][3]=0.f; }

  const int sj0 = (t & 7) * 8;
  const int sm0 = (t >> 3) * 4;
  const u16* vbase = VW + ((size_t)b * 256 + sj0) * 12544 + pq * 256 + sm0;
  const int prow = t >> 1;
  const int pgr0 = (t & 1) * 4;
  const u16* pbase = P + ((size_t)b * 256 + prow) * 256 + (t & 1) * 32;
  u16* psdst = &PS[prow * 64];
  const int pswr = prow & 7;

  for (int jc = 0; jc < 4; ++jc) {
    const int j0 = jc * 64;
    u16x4 rr[8];
    #pragma unroll
    for (int ji = 0; ji < 8; ++ji)
      rr[ji] = *(const u16x4*)(vbase + (size_t)(j0 + ji) * 12544);
    #pragma unroll
    for (int mi = 0; mi < 4; ++mi) {
      u16x8 wv;
      #pragma unroll
      for (int ji = 0; ji < 8; ++ji) wv[ji] = rr[ji][mi];
      const int m = sm0 + mi;
      *(u16x8*)&VT[m * 64 + (((sj0 >> 3) ^ (m & 7)) << 3)] = wv;
    }
    #pragma unroll
    for (int gi = 0; gi < 4; ++gi) {
      const int off = ((pgr0 + gi) ^ pswr) << 3;
      *(u16x8*)(psdst + off) = *(const u16x8*)(pbase + j0 + gi * 8);
    }
    __syncthreads();
    #pragma unroll
    for (int kk = 0; kk < 2; ++kk) {
      s16x8 av[4], bp[8];
      #pragma unroll
      for (int mf = 0; mf < 4; ++mf) {
        const int m = m0w + mf * 16 + a15;
        av[mf] = *(const s16x8*)&VT[m * 64 + (((kk * 4 + g) ^ (m & 7)) << 3)];
      }
      #pragma unroll
      for (int f = 0; f < 8; ++f) {
        const int i = i0w + f * 16 + a15;
        bp[f] = *(const s16x8*)&PS[i * 64 + (((kk * 4 + g) ^ (i & 7)) << 3)];
      }
      #pragma unroll
      for (int mf = 0; mf < 4; ++mf)
        #pragma unroll
        for (int f = 0; f < 8; ++f)
          acc[mf][f] = mfma_bf16(av[mf], bp[f], acc[mf][f]);
    }
    __syncthreads();
  }

  const int pp_ = pq / 7, qq = pq - 7 * pp_;
  #pragma unroll
  for (int f = 0; f < 8; ++f) {
    const int i = i0w + f * 16 + a15;
    const int h1 = i >> 4, w1 = i & 15;
    const size_t gb = ((size_t)b * 12544 + (size_t)((h1 * 7 + pp_) * 112 + w1 * 7 + qq)) * 256;
    #pragma unroll
    for (int mf = 0; mf < 4; ++mf) {
      u16x4 st;
      #pragma unroll
      for (int r = 0; r < 4; ++r) st[r] = f2bf(gelu_f(acc[mf][f][r]));
      *(u16x4*)&GN[gb + m0w + mf * 16 + g * 4] = st;
    }
  }
}

// ---------------- K5: out conv + BN + residual + gelu ----------------
__global__ __launch_bounds__(512, 2) void k_out(
    const u16* __restrict__ GN, const float* __restrict__ wo,
    const float* __restrict__ x, const float* __restrict__ sco,
    const float* __restrict__ sho, float* __restrict__ out)
{
  __shared__ u16 WO[128 * 256];  // [o][k ^ ((o&7)<<3)] bf16, scale-folded
  __shared__ u16 OT[128 * 264];  // [o][px]
  const int b = blockIdx.y;
  const int px0 = blockIdx.x * 256;
  const int t = threadIdx.x;
  const int w = t >> 6, l = t & 63, a15 = l & 15, g = l >> 4;

  {
    const int o = t >> 2, gr0 = (t & 3) * 8;
    const float s = sco[o];
    const float* src = wo + o * 256 + gr0 * 8;
    u16* dr = &WO[o * 256];
    #pragma unroll
    for (int gi = 0; gi < 8; ++gi) {
      const float4 v0 = *(const float4*)(src + gi * 8);
      const float4 v1 = *(const float4*)(src + gi * 8 + 4);
      u16x8 pk;
      pk[0] = f2bf(v0.x * s); pk[1] = f2bf(v0.y * s);
      pk[2] = f2bf(v0.z * s); pk[3] = f2bf(v0.w * s);
      pk[4] = f2bf(v1.x * s); pk[5] = f2bf(v1.y * s);
      pk[6] = f2bf(v1.z * s); pk[7] = f2bf(v1.w * s);
      *(u16x8*)(dr + (((gr0 + gi) ^ (o & 7)) << 3)) = pk;
    }
  }
  __syncthreads();

  const int pw = w >> 1, ow = w & 1;
  const int o0w = ow * 64;
  f32x4 acc[4][4];
  #pragma unroll
  for (int i = 0; i < 4; ++i)
    #pragma unroll
    for (int j = 0; j < 4; ++j) { acc[i][j][0]=0.f; acc[i][j][1]=0.f; acc[i][j][2]=0.f; acc[i][j][3]=0.f; }

  #pragma unroll 1
  for (int ksl = 0; ksl < 8; ++ksl) {
    s16x8 af[4], bw[4];
    #pragma unroll
    for (int pxf = 0; pxf < 4; ++pxf) {
      const int row = px0 + pw * 64 + pxf * 16 + a15;
      af[pxf] = ld8(GN + ((size_t)b * 12544 + row) * 256 + ksl * 32 + g * 8);
    }
    #pragma unroll
    for (int of = 0; of < 4; ++of) {
      const int o = o0w + of * 16 + a15;
      bw[of] = *(const s16x8*)&WO[o * 256 + (((ksl * 4 + g) ^ (o & 7)) << 3)];
    }
    #pragma unroll
    for (int pxf = 0; pxf < 4; ++pxf)
      #pragma unroll
      for (int of = 0; of < 4; ++of)
        acc[pxf][of] = mfma_bf16(af[pxf], bw[of], acc[pxf][of]);
  }

  #pragma unroll
  for (int pxf = 0; pxf < 4; ++pxf)
    #pragma unroll
    for (int of = 0; of < 4; ++of) {
      u16x4 st;
      #pragma unroll
      for (int r = 0; r < 4; ++r) st[r] = f2bf(acc[pxf][of][r]);
      *(u16x4*)&OT[(o0w + of * 16 + a15) * 264 + pw * 64 + pxf * 16 + g * 4] = st;
    }
  __syncthreads();

  const int o2 = t >> 2;
  const float sh = sho[o2];
  const size_t xb = ((size_t)b * 128 + o2) * 12544 + px0;
  #pragma unroll 2
  for (int ii = 0; ii < 16; ++ii) {
    const int po = ii * 16 + (t & 3) * 4;
    const u16x4 zt = *(const u16x4*)&OT[o2 * 264 + po];
    const float4 xv = *(const float4*)(x + xb + po);
    float4 r;
    r.x = gelu_f(bf2f(zt[0]) + sh + xv.x);
    r.y = gelu_f(bf2f(zt[1]) + sh + xv.y);
    r.z = gelu_f(bf2f(zt[2]) + sh + xv.z);
    r.w = gelu_f(bf2f(zt[3]) + sh + xv.w);
    *(float4*)(out + xb + po) = r;
  }
}

extern "C" void kernel_launch(void* const* d_in, const int* in_sizes, int n_in,
                              void* d_out, int out_size, void* d_ws, size_t ws_size,
                              hipStream_t stream) {
  (void)in_sizes; (void)n_in; (void)out_size; (void)ws_size;
  const float* x   = (const float*)d_in[0];
  const float* wq  = (const float*)d_in[1];
  const float* gq  = (const float*)d_in[2];
  const float* bq  = (const float*)d_in[3];
  const float* mq  = (const float*)d_in[4];
  const float* vq  = (const float*)d_in[5];
  const float* wk  = (const float*)d_in[6];
  const float* gk  = (const float*)d_in[7];
  const float* bk  = (const float*)d_in[8];
  const float* mk  = (const float*)d_in[9];
  const float* vk  = (const float*)d_in[10];
  const float* wv  = (const float*)d_in[11];
  const float* gv  = (const float*)d_in[12];
  const float* bv  = (const float*)d_in[13];
  const float* mv  = (const float*)d_in[14];
  const float* vv  = (const float*)d_in[15];
  const float* wo  = (const float*)d_in[16];
  const float* bo  = (const float*)d_in[17];
  const float* go  = (const float*)d_in[18];
  const float* bbo = (const float*)d_in[19];
  const float* mo  = (const float*)d_in[20];
  const float* vo  = (const float*)d_in[21];

  u16* QW = (u16*)d_ws;                 // 32*256*6272 = 51,380,224
  u16* KW = QW + 51380224u;
  u16* VW = KW + 51380224u;             // 32*256*12544 = 102,760,448
  u16* GN = VW + 102760448u;            // 102,760,448
  u16* P  = QW;                          // alias (live after k_dots)
  float* Pp = (float*)GN;                // alias 8*32*256*256 f32 (live k_dots..k_smax)
  u16* wfused = GN;                      // alias 512*128 bf16 (live k_wconv..k_qkv)
  float* sc512 = (float*)(GN + 102760448u);
  float* sh512 = sc512 + 512;
  float* sco = sh512 + 512;
  float* sho = sco + 128;

  k_params<<<1, 512, 0, stream>>>(gq, bq, mq, vq, gk, bk, mk, vk, gv, bv, mv, vv,
                                  bo, go, bbo, mo, vo, sc512, sh512, sco, sho);
  k_wconv<<<64, 256, 0, stream>>>(wq, wk, wv, sc512, wfused);
  k_qkv<<<dim3(49, 32), 256, 0, stream>>>(x, wfused, sh512, QW, KW, VW);
  k_dots<<<dim3(8, 32), 512, 0, stream>>>(QW, KW, Pp);
  k_smax<<<dim3(8, 32), 256, 0, stream>>>(Pp, P);
  k_pv<<<dim3(49, 32), 512, 0, stream>>>(P, VW, GN);
  k_out<<<dim3(49, 32), 512, 0, stream>>>(GN, wo, x, sco, sho, (float*)d_out);
}

// Round 4
// 742.997 us; speedup vs baseline: 2.3032x; 1.0078x over previous
//
#include <hip/hip_runtime.h>

// Windowed attention block (B=32, C=128->256->128, H=W=112, WS=7, T=256 windows).
// fp32 I/O, bf16 MFMA internal.
// ws (616.6MB): QW [32][256 j][49 pq *128c] bf16 | KW same | VW [32][256 j][12544 m] bf16
//               GN [32][12544 px][256 d] bf16 | params f32
// aliases: P bf16 [32][256][256] -> QW base (after k_dots reads QW)
//          Pp f32 [8][32][256][256] -> GN base (before k_pv writes GN)
//          wfused bf16 [512][128] -> GN base (dead before k_dots writes Pp)

typedef unsigned short u16;
typedef unsigned int u32;
typedef short s16x8 __attribute__((ext_vector_type(8)));
typedef float f32x4 __attribute__((ext_vector_type(4)));
typedef u16 u16x8 __attribute__((ext_vector_type(8)));
typedef u16 u16x4 __attribute__((ext_vector_type(4)));

#define EPSV 1e-5f

__device__ __forceinline__ float bf2f(u16 h) {
  u32 u = ((u32)h) << 16;
  return __builtin_bit_cast(float, u);
}
__device__ __forceinline__ u16 f2bf(float f) {
  u32 u = __builtin_bit_cast(u32, f);
  u += 0x7FFFu + ((u >> 16) & 1u);
  return (u16)(u >> 16);
}
__device__ __forceinline__ s16x8 ld8(const u16* p) { return *(const s16x8*)p; }
__device__ __forceinline__ f32x4 mfma_bf16(s16x8 a, s16x8 b, f32x4 c) {
  return __builtin_amdgcn_mfma_f32_16x16x32_bf16(a, b, c, 0, 0, 0);
}
__device__ __forceinline__ float gelu_f(float v) {
  float e = exp2f(-2.3022083f * (v + 0.044715f * v * v * v));
  return v / (1.0f + e);
}

// ---------------- K0: fold BN params ----------------
__global__ void k_params(
    const float* __restrict__ gq, const float* __restrict__ bq, const float* __restrict__ mq, const float* __restrict__ vq,
    const float* __restrict__ gk, const float* __restrict__ bk, const float* __restrict__ mk, const float* __restrict__ vk,
    const float* __restrict__ gv, const float* __restrict__ bv, const float* __restrict__ mv, const float* __restrict__ vv,
    const float* __restrict__ bo, const float* __restrict__ go, const float* __restrict__ bbo, const float* __restrict__ mo,
    const float* __restrict__ vo,
    float* __restrict__ sc512, float* __restrict__ sh512, float* __restrict__ sco, float* __restrict__ sho)
{
  const int i = threadIdx.x;
  if (i < 128) {
    const float s = gq[i] * rsqrtf(vq[i] + EPSV);
    sc512[i] = s;
    sh512[i] = bq[i] - mq[i] * s;
    const float so = go[i] * rsqrtf(vo[i] + EPSV);
    sco[i] = so;
    sho[i] = (bo[i] - mo[i]) * so + bbo[i];
  } else if (i < 256) {
    const int c = i - 128;
    const float s = gk[c] * rsqrtf(vk[c] + EPSV);
    sc512[i] = s;
    sh512[i] = bk[c] - mk[c] * s;
  } else if (i < 512) {
    const int c = i - 256;
    const float s = gv[c] * rsqrtf(vv[c] + EPSV);
    sc512[i] = s;
    sh512[i] = bv[c] - mv[c] * s;
  }
}

// ---------------- K0b: convert+scale-fold QKV weights to bf16 ----------------
__global__ void k_wconv(const float* __restrict__ wq, const float* __restrict__ wk,
                        const float* __restrict__ wv, const float* __restrict__ sc512,
                        u16* __restrict__ wfused)
{
  const int idx4 = (blockIdx.x * 256 + threadIdx.x) * 4;  // 0..65532
  const int co = idx4 >> 7, c = idx4 & 127;
  const float* src = (co < 128) ? (wq + co * 128 + c)
                   : (co < 256) ? (wk + (co - 128) * 128 + c)
                                : (wv + (co - 256) * 128 + c);
  const float s = sc512[co];
  const float4 v = *(const float4*)src;
  u16x4 r;
  r[0] = f2bf(v.x * s); r[1] = f2bf(v.y * s);
  r[2] = f2bf(v.z * s); r[3] = f2bf(v.w * s);
  *(u16x4*)(wfused + idx4) = r;
}

// ---------------- K1: QKV projection (+folded BN) ----------------
// 4 phases of 128 co: MFMA -> LDS out-tile -> coalesced 256B-row flush.
__global__ __launch_bounds__(256, 2) void k_qkv(
    const float* __restrict__ x, const u16* __restrict__ wfused,
    const float* __restrict__ sh512,
    u16* __restrict__ QW, u16* __restrict__ KW, u16* __restrict__ VW)
{
  __shared__ u16 XT[256 * 128];  // stage x [px][c ^ ((px&15)<<3)]; reused as out tile [px][co']
  const int b = blockIdx.y;
  const int px0 = blockIdx.x * 256;
  const int t = threadIdx.x;

  // stage x tile (NCHW fp32 -> LDS bf16 transposed, XOR-swizzled)
  {
    const float* xp = x + (size_t)b * 128u * 12544u + (size_t)(px0 + t);
    const int sw = (t & 15) << 3;
    #pragma unroll 8
    for (int c = 0; c < 128; c += 4) {
      u16x4 pk;
      pk[0] = f2bf(xp[(size_t)(c + 0) * 12544u]);
      pk[1] = f2bf(xp[(size_t)(c + 1) * 12544u]);
      pk[2] = f2bf(xp[(size_t)(c + 2) * 12544u]);
      pk[3] = f2bf(xp[(size_t)(c + 3) * 12544u]);
      *(u16x4*)&XT[t * 128 + (c ^ sw)] = pk;
    }
  }
  __syncthreads();

  const int w = t >> 6, l = t & 63, a15 = l & 15, g = l >> 4;

  // A fragments into registers; XT is dead afterwards
  s16x8 af[4][4];
  #pragma unroll
  for (int pxt = 0; pxt < 4; ++pxt) {
    const int row = w * 64 + pxt * 16 + a15;
    const int sw = (row & 15) << 3;
    #pragma unroll
    for (int ks = 0; ks < 4; ++ks) {
      const int cc = ks * 32 + g * 8;
      af[pxt][ks] = *(const s16x8*)&XT[row * 128 + (cc ^ sw)];
    }
  }
  __syncthreads();

  // per-thread output row (thread t owns pixel px0+t)
  const int px = px0 + t;
  const int hh = px / 112, ww = px - hh * 112;
  const int h1 = hh / 7, p = hh - h1 * 7;
  const int w1 = ww / 7, q = ww - w1 * 7;
  const int j = h1 * 16 + w1, pq = p * 7 + q;
  u16* const qrow = QW + ((size_t)(b * 256 + j) * 49 + pq) * 128;
  u16* const krow = KW + ((size_t)(b * 256 + j) * 49 + pq) * 128;
  u16* const vrow = VW + (size_t)(b * 256 + j) * 12544 + pq * 256;

  #pragma unroll 1
  for (int phase = 0; phase < 4; ++phase) {
    // double-buffered weight fragments over cot8
    s16x8 bcur[4];
    {
      const u16* wrow = wfused + (u32)(phase * 128 + a15) * 128u;
      #pragma unroll
      for (int ks = 0; ks < 4; ++ks) bcur[ks] = ld8(wrow + ks * 32 + g * 8);
    }
    #pragma unroll 1
    for (int cot8 = 0; cot8 < 8; ++cot8) {
      s16x8 bnext[4];
      if (cot8 < 7) {
        const u16* wrow = wfused + (u32)(phase * 128 + (cot8 + 1) * 16 + a15) * 128u;
        #pragma unroll
        for (int ks = 0; ks < 4; ++ks) bnext[ks] = ld8(wrow + ks * 32 + g * 8);
      }
      f32x4 acc[4];
      #pragma unroll
      for (int pxt = 0; pxt < 4; ++pxt) { acc[pxt][0]=0.f; acc[pxt][1]=0.f; acc[pxt][2]=0.f; acc[pxt][3]=0.f; }
      #pragma unroll
      for (int ks = 0; ks < 4; ++ks)
        #pragma unroll
        for (int pxt = 0; pxt < 4; ++pxt)
          acc[pxt] = mfma_bf16(af[pxt][ks], bcur[ks], acc[pxt]);

      const float sh = sh512[phase * 128 + cot8 * 16 + a15];
      const int co = cot8 * 16 + a15;  // within-phase channel
      #pragma unroll
      for (int pxt = 0; pxt < 4; ++pxt) {
        #pragma unroll
        for (int r = 0; r < 4; ++r) {
          const int pxl = w * 64 + pxt * 16 + g * 4 + r;
          XT[pxl * 128 + (co ^ ((pxl & 15) << 3))] = f2bf(acc[pxt][r] + sh);
        }
      }
      #pragma unroll
      for (int ks = 0; ks < 4; ++ks) bcur[ks] = bnext[ks];
    }
    __syncthreads();
    // flush: thread t writes its full 128-channel row (256B contiguous)
    {
      u16* dst = (phase == 0) ? qrow : (phase == 1) ? krow : vrow + (phase - 2) * 128;
      const int sw = (t & 15) << 3;
      #pragma unroll
      for (int c8 = 0; c8 < 16; ++c8)
        *(u16x8*)(dst + c8 * 8) = *(const u16x8*)&XT[t * 128 + ((c8 * 8) ^ sw)];
    }
    __syncthreads();
  }
}

// ---------------- K2: dots partials (split-K over pq) ----------------
// grid (8 ks, 32 b), 512 thr. Block: full 256i x 256j over k = 768 (or 896).
__global__ __launch_bounds__(512, 2) void k_dots(
    const u16* __restrict__ QW, const u16* __restrict__ KW, float* __restrict__ Pp)
{
  __shared__ u16 QS[256 * 64];  // [i][k ^ ((i&7)<<3)]
  __shared__ u16 KS[256 * 64];
  const int b = blockIdx.y, ks = blockIdx.x;
  const int nch = (ks == 7) ? 14 : 12;
  const int t = threadIdx.x;
  const int w = t >> 6, l = t & 63, a15 = l & 15, g = l >> 4;
  const int i0w = (w >> 1) * 64, j0w = (w & 1) * 128;

  f32x4 acc[4][8];
  #pragma unroll
  for (int i = 0; i < 4; ++i)
    #pragma unroll
    for (int j = 0; j < 8; ++j) { acc[i][j][0]=0.f; acc[i][j][1]=0.f; acc[i][j][2]=0.f; acc[i][j][3]=0.f; }

  const int srow = t >> 1;
  const int sgr0 = (t & 1) * 4;
  const size_t kb = (size_t)ks * 768 + (size_t)((t & 1) * 32);
  const u16* qsrc = QW + ((size_t)b * 256 + srow) * 6272 + kb;
  const u16* ksrc = KW + ((size_t)b * 256 + srow) * 6272 + kb;
  u16* qdst = &QS[srow * 64];
  u16* kdst = &KS[srow * 64];
  const int swr = srow & 7;

  for (int ch = 0; ch < nch; ++ch) {
    const int k0 = ch * 64;
    #pragma unroll
    for (int gi = 0; gi < 4; ++gi) {
      const int off = ((sgr0 + gi) ^ swr) << 3;
      *(u16x8*)(qdst + off) = *(const u16x8*)(qsrc + k0 + gi * 8);
      *(u16x8*)(kdst + off) = *(const u16x8*)(ksrc + k0 + gi * 8);
    }
    __syncthreads();
    #pragma unroll
    for (int kk = 0; kk < 2; ++kk) {
      s16x8 af[4], bfr[8];
      #pragma unroll
      for (int i4 = 0; i4 < 4; ++i4) {
        const int ir = i0w + i4 * 16 + a15;
        af[i4] = *(const s16x8*)&QS[ir * 64 + (((kk * 4 + g) ^ (ir & 7)) << 3)];
      }
      #pragma unroll
      for (int j8 = 0; j8 < 8; ++j8) {
        const int jr = j0w + j8 * 16 + a15;
        bfr[j8] = *(const s16x8*)&KS[jr * 64 + (((kk * 4 + g) ^ (jr & 7)) << 3)];
      }
      #pragma unroll
      for (int i4 = 0; i4 < 4; ++i4)
        #pragma unroll
        for (int j8 = 0; j8 < 8; ++j8)
          acc[i4][j8] = mfma_bf16(af[i4], bfr[j8], acc[i4][j8]);
    }
    __syncthreads();
  }

  float* pp = Pp + ((size_t)ks * 32 + b) * 256 * 256;
  #pragma unroll
  for (int i4 = 0; i4 < 4; ++i4)
    #pragma unroll
    for (int r = 0; r < 4; ++r) {
      const int ir = i0w + i4 * 16 + g * 4 + r;
      #pragma unroll
      for (int j8 = 0; j8 < 8; ++j8)
        pp[(size_t)ir * 256 + j0w + j8 * 16 + a15] = acc[i4][j8][r];
    }
}

// ---------------- K3: reduce partials + softmax -> P bf16 ----------------
__global__ __launch_bounds__(256, 4) void k_smax(const float* __restrict__ Pp, u16* __restrict__ P)
{
  const int b = blockIdx.y, it = blockIdx.x;
  const int t = threadIdx.x;
  const int row = it * 32 + (t >> 3);
  const int cg = t & 7;
  const size_t rb = ((size_t)b * 256 + row) * 256 + cg * 32;

  f32x4 s[8];
  #pragma unroll
  for (int cc = 0; cc < 8; ++cc) { s[cc][0]=0.f; s[cc][1]=0.f; s[cc][2]=0.f; s[cc][3]=0.f; }
  #pragma unroll 1
  for (int ks = 0; ks < 8; ++ks) {
    const float* src = Pp + (size_t)ks * 32 * 256 * 256 + rb;
    #pragma unroll
    for (int cc = 0; cc < 8; ++cc)
      s[cc] += *(const f32x4*)(src + cc * 4);
  }
  float m = -1e30f;
  #pragma unroll
  for (int cc = 0; cc < 8; ++cc)
    m = fmaxf(m, fmaxf(fmaxf(s[cc][0], s[cc][1]), fmaxf(s[cc][2], s[cc][3])));
  m = fmaxf(m, __shfl_xor(m, 1));
  m = fmaxf(m, __shfl_xor(m, 2));
  m = fmaxf(m, __shfl_xor(m, 4));
  const float CEXP = 0.18033688f;  // 0.125*log2(e)
  float sum = 0.f;
  #pragma unroll
  for (int cc = 0; cc < 8; ++cc)
    #pragma unroll
    for (int e = 0; e < 4; ++e) {
      const float p = exp2f((s[cc][e] - m) * CEXP);
      s[cc][e] = p;
      sum += p;
    }
  sum += __shfl_xor(sum, 1);
  sum += __shfl_xor(sum, 2);
  sum += __shfl_xor(sum, 4);
  const float inv = 1.0f / sum;
  u16* dst = P + rb;
  #pragma unroll
  for (int cc = 0; cc < 8; cc += 2) {
    u16x8 o;
    o[0] = f2bf(s[cc][0] * inv);     o[1] = f2bf(s[cc][1] * inv);
    o[2] = f2bf(s[cc][2] * inv);     o[3] = f2bf(s[cc][3] * inv);
    o[4] = f2bf(s[cc + 1][0] * inv); o[5] = f2bf(s[cc + 1][1] * inv);
    o[6] = f2bf(s[cc + 1][2] * inv); o[7] = f2bf(s[cc + 1][3] * inv);
    *(u16x8*)(dst + cc * 4) = o;
  }
}

// ---------------- K4: PV + gelu -> GN ----------------
// grid (49 pq, 32 b), 512 thr. Block: 256 m (=d within pq) x 256 i, K=256 j in 4 chunks.
__global__ __launch_bounds__(512, 2) void k_pv(
    const u16* __restrict__ P, const u16* __restrict__ VW, u16* __restrict__ GN)
{
  __shared__ u16 VT[256 * 64];  // [m][j ^ ((m&7)<<3)]
  __shared__ u16 PS[256 * 64];  // [i][j ^ ((i&7)<<3)]
  const int b = blockIdx.y, pq = blockIdx.x;
  const int t = threadIdx.x;
  const int w = t >> 6, l = t & 63, a15 = l & 15, g = l >> 4;
  const int m0w = (w >> 1) * 64, i0w = (w & 1) * 128;

  f32x4 acc[4][8];  // [mf][if]
  #pragma unroll
  for (int i = 0; i < 4; ++i)
    #pragma unroll
    for (int j = 0; j < 8; ++j) { acc[i][j][0]=0.f; acc[i][j][1]=0.f; acc[i][j][2]=0.f; acc[i][j][3]=0.f; }

  const int sj0 = (t & 7) * 8;
  const int sm0 = (t >> 3) * 4;
  const u16* vbase = VW + ((size_t)b * 256 + sj0) * 12544 + pq * 256 + sm0;
  const int prow = t >> 1;
  const int pgr0 = (t & 1) * 4;
  const u16* pbase = P + ((size_t)b * 256 + prow) * 256 + (t & 1) * 32;
  u16* psdst = &PS[prow * 64];
  const int pswr = prow & 7;

  for (int jc = 0; jc < 4; ++jc) {
    const int j0 = jc * 64;
    u16x4 rr[8];
    #pragma unroll
    for (int ji = 0; ji < 8; ++ji)
      rr[ji] = *(const u16x4*)(vbase + (size_t)(j0 + ji) * 12544);
    #pragma unroll
    for (int mi = 0; mi < 4; ++mi) {
      u16x8 wv;
      #pragma unroll
      for (int ji = 0; ji < 8; ++ji) wv[ji] = rr[ji][mi];
      const int m = sm0 + mi;
      *(u16x8*)&VT[m * 64 + (((sj0 >> 3) ^ (m & 7)) << 3)] = wv;
    }
    #pragma unroll
    for (int gi = 0; gi < 4; ++gi) {
      const int off = ((pgr0 + gi) ^ pswr) << 3;
      *(u16x8*)(psdst + off) = *(const u16x8*)(pbase + j0 + gi * 8);
    }
    __syncthreads();
    #pragma unroll
    for (int kk = 0; kk < 2; ++kk) {
      s16x8 av[4], bp[8];
      #pragma unroll
      for (int mf = 0; mf < 4; ++mf) {
        const int m = m0w + mf * 16 + a15;
        av[mf] = *(const s16x8*)&VT[m * 64 + (((kk * 4 + g) ^ (m & 7)) << 3)];
      }
      #pragma unroll
      for (int f = 0; f < 8; ++f) {
        const int i = i0w + f * 16 + a15;
        bp[f] = *(const s16x8*)&PS[i * 64 + (((kk * 4 + g) ^ (i & 7)) << 3)];
      }
      #pragma unroll
      for (int mf = 0; mf < 4; ++mf)
        #pragma unroll
        for (int f = 0; f < 8; ++f)
          acc[mf][f] = mfma_bf16(av[mf], bp[f], acc[mf][f]);
    }
    __syncthreads();
  }

  const int pp_ = pq / 7, qq = pq - 7 * pp_;
  #pragma unroll
  for (int f = 0; f < 8; ++f) {
    const int i = i0w + f * 16 + a15;
    const int h1 = i >> 4, w1 = i & 15;
    const size_t gb = ((size_t)b * 12544 + (size_t)((h1 * 7 + pp_) * 112 + w1 * 7 + qq)) * 256;
    #pragma unroll
    for (int mf = 0; mf < 4; ++mf) {
      u16x4 st;
      #pragma unroll
      for (int r = 0; r < 4; ++r) st[r] = f2bf(gelu_f(acc[mf][f][r]));
      *(u16x4*)&GN[gb + m0w + mf * 16 + g * 4] = st;
    }
  }
}

// ---------------- K5: out conv + BN + residual + gelu ----------------
__global__ __launch_bounds__(512, 2) void k_out(
    const u16* __restrict__ GN, const float* __restrict__ wo,
    const float* __restrict__ x, const float* __restrict__ sco,
    const float* __restrict__ sho, float* __restrict__ out)
{
  __shared__ u16 WO[128 * 256];  // [o][k ^ ((o&7)<<3)] bf16, scale-folded
  __shared__ u16 OT[128 * 264];  // [o][px]
  const int b = blockIdx.y;
  const int px0 = blockIdx.x * 256;
  const int t = threadIdx.x;
  const int w = t >> 6, l = t & 63, a15 = l & 15, g = l >> 4;

  {
    const int o = t >> 2, gr0 = (t & 3) * 8;
    const float s = sco[o];
    const float* src = wo + o * 256 + gr0 * 8;
    u16* dr = &WO[o * 256];
    #pragma unroll
    for (int gi = 0; gi < 8; ++gi) {
      const float4 v0 = *(const float4*)(src + gi * 8);
      const float4 v1 = *(const float4*)(src + gi * 8 + 4);
      u16x8 pk;
      pk[0] = f2bf(v0.x * s); pk[1] = f2bf(v0.y * s);
      pk[2] = f2bf(v0.z * s); pk[3] = f2bf(v0.w * s);
      pk[4] = f2bf(v1.x * s); pk[5] = f2bf(v1.y * s);
      pk[6] = f2bf(v1.z * s); pk[7] = f2bf(v1.w * s);
      *(u16x8*)(dr + (((gr0 + gi) ^ (o & 7)) << 3)) = pk;
    }
  }
  __syncthreads();

  const int pw = w >> 1, ow = w & 1;
  const int o0w = ow * 64;
  f32x4 acc[4][4];
  #pragma unroll
  for (int i = 0; i < 4; ++i)
    #pragma unroll
    for (int j = 0; j < 4; ++j) { acc[i][j][0]=0.f; acc[i][j][1]=0.f; acc[i][j][2]=0.f; acc[i][j][3]=0.f; }

  #pragma unroll 1
  for (int ksl = 0; ksl < 8; ++ksl) {
    s16x8 af[4], bw[4];
    #pragma unroll
    for (int pxf = 0; pxf < 4; ++pxf) {
      const int row = px0 + pw * 64 + pxf * 16 + a15;
      af[pxf] = ld8(GN + ((size_t)b * 12544 + row) * 256 + ksl * 32 + g * 8);
    }
    #pragma unroll
    for (int of = 0; of < 4; ++of) {
      const int o = o0w + of * 16 + a15;
      bw[of] = *(const s16x8*)&WO[o * 256 + (((ksl * 4 + g) ^ (o & 7)) << 3)];
    }
    #pragma unroll
    for (int pxf = 0; pxf < 4; ++pxf)
      #pragma unroll
      for (int of = 0; of < 4; ++of)
        acc[pxf][of] = mfma_bf16(af[pxf], bw[of], acc[pxf][of]);
  }

  #pragma unroll
  for (int pxf = 0; pxf < 4; ++pxf)
    #pragma unroll
    for (int of = 0; of < 4; ++of) {
      u16x4 st;
      #pragma unroll
      for (int r = 0; r < 4; ++r) st[r] = f2bf(acc[pxf][of][r]);
      *(u16x4*)&OT[(o0w + of * 16 + a15) * 264 + pw * 64 + pxf * 16 + g * 4] = st;
    }
  __syncthreads();

  const int o2 = t >> 2;
  const float sh = sho[o2];
  const size_t xb = ((size_t)b * 128 + o2) * 12544 + px0;
  #pragma unroll 2
  for (int ii = 0; ii < 16; ++ii) {
    const int po = ii * 16 + (t & 3) * 4;
    const u16x4 zt = *(const u16x4*)&OT[o2 * 264 + po];
    const float4 xv = *(const float4*)(x + xb + po);
    float4 r;
    r.x = gelu_f(bf2f(zt[0]) + sh + xv.x);
    r.y = gelu_f(bf2f(zt[1]) + sh + xv.y);
    r.z = gelu_f(bf2f(zt[2]) + sh + xv.z);
    r.w = gelu_f(bf2f(zt[3]) + sh + xv.w);
    *(float4*)(out + xb + po) = r;
  }
}

extern "C" void kernel_launch(void* const* d_in, const int* in_sizes, int n_in,
                              void* d_out, int out_size, void* d_ws, size_t ws_size,
                              hipStream_t stream) {
  (void)in_sizes; (void)n_in; (void)out_size; (void)ws_size;
  const float* x   = (const float*)d_in[0];
  const float* wq  = (const float*)d_in[1];
  const float* gq  = (const float*)d_in[2];
  const float* bq  = (const float*)d_in[3];
  const float* mq  = (const float*)d_in[4];
  const float* vq  = (const float*)d_in[5];
  const float* wk  = (const float*)d_in[6];
  const float* gk  = (const float*)d_in[7];
  const float* bk  = (const float*)d_in[8];
  const float* mk  = (const float*)d_in[9];
  const float* vk  = (const float*)d_in[10];
  const float* wv  = (const float*)d_in[11];
  const float* gv  = (const float*)d_in[12];
  const float* bv  = (const float*)d_in[13];
  const float* mv  = (const float*)d_in[14];
  const float* vv  = (const float*)d_in[15];
  const float* wo  = (const float*)d_in[16];
  const float* bo  = (const float*)d_in[17];
  const float* go  = (const float*)d_in[18];
  const float* bbo = (const float*)d_in[19];
  const float* mo  = (const float*)d_in[20];
  const float* vo  = (const float*)d_in[21];

  u16* QW = (u16*)d_ws;                 // 32*256*6272 = 51,380,224
  u16* KW = QW + 51380224u;
  u16* VW = KW + 51380224u;             // 32*256*12544 = 102,760,448
  u16* GN = VW + 102760448u;            // 102,760,448
  u16* P  = QW;                          // alias (live after k_dots)
  float* Pp = (float*)GN;                // alias 8*32*256*256 f32 (live k_dots..k_smax)
  u16* wfused = GN;                      // alias 512*128 bf16 (live k_wconv..k_qkv)
  float* sc512 = (float*)(GN + 102760448u);
  float* sh512 = sc512 + 512;
  float* sco = sh512 + 512;
  float* sho = sco + 128;

  k_params<<<1, 512, 0, stream>>>(gq, bq, mq, vq, gk, bk, mk, vk, gv, bv, mv, vv,
                                  bo, go, bbo, mo, vo, sc512, sh512, sco, sho);
  k_wconv<<<64, 256, 0, stream>>>(wq, wk, wv, sc512, wfused);
  k_qkv<<<dim3(49, 32), 256, 0, stream>>>(x, wfused, sh512, QW, KW, VW);
  k_dots<<<dim3(8, 32), 512, 0, stream>>>(QW, KW, Pp);
  k_smax<<<dim3(8, 32), 256, 0, stream>>>(Pp, P);
  k_pv<<<dim3(49, 32), 512, 0, stream>>>(P, VW, GN);
  k_out<<<dim3(49, 32), 512, 0, stream>>>(GN, wo, x, sco, sho, (float*)d_out);
}